// Round 12
// baseline (240.354 us; speedup 1.0000x reference)
//
#include <hip/hip_runtime.h>

// Problem constants (from reference setup_inputs)
constexpr int B_   = 2;
constexpr int CIN  = 64;
constexpr int N    = 128;
constexpr int T    = 24;
constexpr int HID  = 64;
constexpr int COUT = 64;
constexpr int NT   = N * T;            // 3072
constexpr int ROWS = B_ * N * T;       // 6144
constexpr int BT   = B_ * T;           // 48
constexpr int MLP_BLOCKS = ROWS / 4;   // 1536
constexpr int TRS_BLOCKS = B_ * N;     // 256
constexpr int AMP_MLP = 20;            // MLP-section amplification
constexpr int AMP_ATT = 50;            // att-section amplification

typedef __attribute__((ext_vector_type(8))) short short8;
typedef __attribute__((ext_vector_type(4))) float f32x4;

__device__ inline unsigned short f2bf(float f) {
    unsigned u = __float_as_uint(f);
    return (unsigned short)((u + 0x7FFFu + ((u >> 16) & 1u)) >> 16);
}

// ---------------------------------------------------------------------------
// MLP section body (R9-identical), parameterized by row group.
// ---------------------------------------------------------------------------
__device__ __forceinline__ void mlp_body(
    int grp, int tid,
    const float* __restrict__ x,  const float* __restrict__ W1,
    const float* __restrict__ b1, const float* __restrict__ W2,
    const float* __restrict__ b2,
    float* __restrict__ mvb2, float* __restrict__ mh,
    float (*xs)[64], float (*hs)[64])
{
    const int r   = tid >> 6;
    const int k   = tid & 63;
    const int row = grp * 4 + r;
    const int b   = row / NT;
    const int nt  = row - b * NT;

    xs[r][k] = x[(size_t)b * CIN * NT + (size_t)k * NT + nt];
    __syncthreads();

    float h = b1[k];
#pragma unroll
    for (int c = 0; c < CIN; ++c) h += xs[r][c] * W1[c * HID + k];
    hs[r][k] = h;
    __syncthreads();

    float mv = 0.f, mhv = 0.f;
#pragma unroll
    for (int q = 0; q < HID; ++q) {
        const float hq = hs[r][q];
        mv  += hq * W2[q * COUT + k];
        mhv += hq * W2[(HID + q) * COUT + k];
    }
    const int n  = nt / T;
    const int t  = nt - n * T;
    const int bt = b * T + t;
    const size_t o = ((size_t)bt * N + n) * COUT + k;
    mvb2[o] = mv + b2[k];
    mh[o]   = mhv;
}

// ---------------------------------------------------------------------------
// att-transpose section body (R9-identical), parameterized by (b,i) index.
// ---------------------------------------------------------------------------
__device__ __forceinline__ void atts_body(
    int tb, int tid,
    const float* __restrict__ att,
    unsigned int* __restrict__ attT32, float* __restrict__ asum_g,
    float (*ts)[T + 1], float (*psum)[8])
{
    const int b = tb >> 7;
    const int i = tb & 127;

    const float* ab = att + ((size_t)b * N + i) * NT;
#pragma unroll
    for (int u = 0; u < 12; ++u) {
        const int idx = tid + 256 * u;
        const int j   = idx / T;
        const int t   = idx - j * T;
        ts[j][t] = ab[idx];
    }
    __syncthreads();

#pragma unroll
    for (int u = 0; u < 6; ++u) {
        const int e2 = tid + 256 * u;
        const int t  = e2 >> 6;
        const int jp = e2 & 63;
        const int j  = jp * 2;
        const unsigned pk = (unsigned)f2bf(ts[j][t])
                          | ((unsigned)f2bf(ts[j + 1][t]) << 16);
        attT32[((size_t)(b * T + t) * N + i) * 64 + jp] = pk;
    }
    if (tid < 192) {
        const int t = tid >> 3;
        const int p = tid & 7;
        float s = 0.f;
#pragma unroll
        for (int q = 0; q < 16; ++q) s += ts[p * 16 + q][t];
        psum[t][p] = s;
    }
    __syncthreads();
    if (tid < T) {
        float s = 0.f;
#pragma unroll
        for (int p = 0; p < 8; ++p) s += psum[tid][p];
        asum_g[(size_t)(b * T + tid) * N + i] = s;
    }
}

// ---------------------------------------------------------------------------
// k_prep: EXACT R9 behavior (MLP blocks + att blocks), via the shared bodies.
// ---------------------------------------------------------------------------
__global__ __launch_bounds__(256) void k_prep(
    const float* __restrict__ x,   const float* __restrict__ att,
    const float* __restrict__ W1,  const float* __restrict__ b1,
    const float* __restrict__ W2,  const float* __restrict__ b2,
    float* __restrict__ mvb2, float* __restrict__ mh,
    unsigned int* __restrict__ attT32, float* __restrict__ asum_g)
{
    __shared__ float smem[N * (T + 1) + T * 8];   // max of both sections
    const int tid = threadIdx.x;

    if (blockIdx.x < MLP_BLOCKS) {
        float (*xs)[64] = (float (*)[64])smem;
        float (*hs)[64] = (float (*)[64])(smem + 4 * 64);
        mlp_body(blockIdx.x, tid, x, W1, b1, W2, b2, mvb2, mh, xs, hs);
    } else {
        float (*ts)[T + 1] = (float (*)[T + 1])smem;
        float (*psum)[8]   = (float (*)[8])(smem + N * (T + 1));
        atts_body(blockIdx.x - MLP_BLOCKS, tid, att, attT32, asum_g, ts, psum);
    }
}

// ---------------------------------------------------------------------------
// Amplified MLP-only kernel: AMP_MLP x 1536 blocks, dummy writes.
// rocprof row dur / AMP_MLP = true MLP-section cost.
// ---------------------------------------------------------------------------
__global__ __launch_bounds__(256) void k_mlp_amp(
    const float* __restrict__ x,  const float* __restrict__ W1,
    const float* __restrict__ b1, const float* __restrict__ W2,
    const float* __restrict__ b2,
    float* __restrict__ mvb2_d, float* __restrict__ mh_d)
{
    __shared__ float xs[4][64];
    __shared__ float hs[4][64];
    mlp_body(blockIdx.x % MLP_BLOCKS, threadIdx.x, x, W1, b1, W2, b2,
             mvb2_d, mh_d, xs, hs);
}

// ---------------------------------------------------------------------------
// Amplified att-section-only kernel: AMP_ATT x 256 blocks, dummy writes.
// ---------------------------------------------------------------------------
__global__ __launch_bounds__(256) void k_atts_amp(
    const float* __restrict__ att,
    unsigned int* __restrict__ attT32_d, float* __restrict__ asum_d)
{
    __shared__ float ts[N][T + 1];
    __shared__ float psum[T][8];
    atts_body(blockIdx.x % TRS_BLOCKS, threadIdx.x, att, attT32_d, asum_d,
              ts, psum);
}

// ---------------------------------------------------------------------------
// k_att: EXACT R9 copy.
// ---------------------------------------------------------------------------
__global__ __launch_bounds__(256) void k_att(
    const unsigned short* __restrict__ attTb,
    const float* __restrict__ mh,
    const float* __restrict__ mvb2,
    const float* __restrict__ asum_g,
    float* __restrict__ out)
{
    __shared__ unsigned short mhs[COUT][136];

    const int blk   = blockIdx.x;
    const int itile = blk & 7;
    const int bt    = blk >> 3;
    const int b     = bt / T;
    const int t     = bt - b * T;

    const int tid  = threadIdx.x;
    const int w    = tid >> 6;
    const int lane = tid & 63;
    const int c16  = lane & 15;
    const int q4   = lane >> 4;
    const int cc   = w * 16 + c16;

    {
        const float* src = mh + (size_t)bt * N * COUT;
#pragma unroll
        for (int u = 0; u < 32; ++u) {
            const int v = tid + 256 * u;
            const int j = v >> 6;
            const int c = v & 63;
            mhs[c][j] = f2bf(src[v]);
        }
    }
    __syncthreads();

    const unsigned short* arow = attTb + ((size_t)bt * N + itile * 16 + c16) * N;

    f32x4 acc = {0.f, 0.f, 0.f, 0.f};
#pragma unroll
    for (int ks = 0; ks < 4; ++ks) {
        const short8 a  = *(const short8*)(arow + ks * 32 + q4 * 8);
        const short8 bb = *(const short8*)(&mhs[cc][ks * 32 + q4 * 8]);
        acc = __builtin_amdgcn_mfma_f32_16x16x32_bf16(a, bb, acc, 0, 0, 0);
    }

    const int il0 = itile * 16 + q4 * 4;
    const f32x4 as4 = *(const f32x4*)(asum_g + (size_t)bt * N + il0);

    float* ob = out + (((size_t)b * COUT + cc) * N + il0) * T + t;
#pragma unroll
    for (int e = 0; e < 4; ++e) {
        const float mb = mvb2[((size_t)bt * N + il0 + e) * COUT + cc];
        ob[e * T] = acc[e] + as4[e] * mb;
    }
}

// ---------------------------------------------------------------------------
// R12 = R9 (real output) + two amplified diagnostic dispatches (dummy writes,
// run AFTER the real pipeline; deterministic; out untouched).
// ---------------------------------------------------------------------------
extern "C" void kernel_launch(void* const* d_in, const int* in_sizes, int n_in,
                              void* d_out, int out_size, void* d_ws, size_t ws_size,
                              hipStream_t stream)
{
    const float* x   = (const float*)d_in[0];
    const float* att = (const float*)d_in[1];
    const float* W1  = (const float*)d_in[2];
    const float* b1  = (const float*)d_in[3];
    const float* W2  = (const float*)d_in[4];
    const float* b2  = (const float*)d_in[5];
    float* out = (float*)d_out;

    // Workspace layout — identical to R9:
    char* ws = (char*)d_ws;
    float*        mvb2   = (float*)ws;                        // 1,572,864 B
    float*        mh     = (float*)(ws + 1572864);            // 1,572,864 B
    float*        asum_g = (float*)(ws + 3145728);            //    24,576 B
    unsigned int* attT32 = (unsigned int*)(ws + 3170304);     // 1,572,864 B
    const unsigned short* attTb = (const unsigned short*)attT32;

    // Dummy region for amplified writes:
    char* dmy = ws + 8388608;
    float*        mvb2_d   = (float*)dmy;
    float*        mh_d     = (float*)(dmy + 1572864);
    float*        asum_d   = (float*)(dmy + 3145728);
    unsigned int* attT32_d = (unsigned int*)(dmy + 3170304);

    // Real pipeline (R9-identical).
    k_prep<<<MLP_BLOCKS + TRS_BLOCKS, 256, 0, stream>>>(
        x, att, W1, b1, W2, b2, mvb2, mh, attT32, asum_g);
    k_att<<<BT * 8, 256, 0, stream>>>(attTb, mh, mvb2, asum_g, out);

    // Diagnostic amplified dispatches (each gets its own rocprof row).
    k_mlp_amp<<<MLP_BLOCKS * AMP_MLP, 256, 0, stream>>>(
        x, W1, b1, W2, b2, mvb2_d, mh_d);
    k_atts_amp<<<TRS_BLOCKS * AMP_ATT, 256, 0, stream>>>(
        att, attT32_d, asum_d);
}

// Round 13
// 18.685 us; speedup vs baseline: 12.8633x; 12.8633x over previous
//
#include <hip/hip_runtime.h>

// Problem constants
constexpr int B_   = 2;
constexpr int CIN  = 64;
constexpr int N    = 128;
constexpr int T    = 24;
constexpr int HID  = 64;
constexpr int COUT = 64;
constexpr int NT   = N * T;             // 3072
constexpr int BT   = B_ * T;            // 48
constexpr int ATT_BLOCKS = B_ * N;      // 256
constexpr int XT_BLOCKS  = 32;          // (b, n-chunk of 8)
constexpr int WF_BLOCKS  = 16;          // (half, 8-col chunk)
constexpr int PREP_BLOCKS = ATT_BLOCKS + XT_BLOCKS + WF_BLOCKS;  // 304

typedef __attribute__((ext_vector_type(8))) short short8;   // 8 bf16 MFMA frag
typedef __attribute__((ext_vector_type(4))) float f32x4;

__device__ inline unsigned short f2bf(float f) {   // RNE float->bf16
    unsigned u = __float_as_uint(f);
    return (unsigned short)((u + 0x7FFFu + ((u >> 16) & 1u)) >> 16);
}

// ---------------------------------------------------------------------------
// k_prep (304 blocks), three sections:
//  [0,256):   att[b,0,i,j,t] -> attT bf16 [bt][i][j] + asum f32  (anchored 0.7us)
//  [256,288): x[b,c',n,t] -> xT bf16 [bt][n][c']  (R7 section + LDS pad fix)
//  [288,304): fused weights via LDS-staged PARALLEL blocks (not R7's serial):
//             WfT_{v,h}[c][c'] bf16 = (W1 @ W2half)^T ; bh, bvb2 biases.
//             MLP is linear (no activation) so mv = xp@Wfv+bvb2, mh = xp@Wfh+bh.
// ---------------------------------------------------------------------------
__global__ __launch_bounds__(256) void k_prep(
    const float* __restrict__ x,
    const float* __restrict__ att,
    const float* __restrict__ W1,
    const float* __restrict__ b1,
    const float* __restrict__ W2,
    const float* __restrict__ b2,
    unsigned* __restrict__ xT32,       // [48][128][32] u32 (bf16 pairs over c')
    unsigned* __restrict__ attT32,     // [48][128][64] u32 (bf16 pairs over j)
    float* __restrict__ asum_g,        // [48][128]
    unsigned short* __restrict__ WfvT, // [64][64] bf16, k-major rows
    unsigned short* __restrict__ WfhT, // [64][64]
    float* __restrict__ bvb2,
    float* __restrict__ bh)
{
    __shared__ __align__(16) unsigned smem_u32[8320];   // 33.3 KB, aliased
    const int tid = threadIdx.x;
    const int blk = blockIdx.x;

    if (blk < ATT_BLOCKS) {
        // ---- att transpose + row-sum (R12-anchored verbatim) ----
        float* ts   = (float*)smem_u32;          // [128][25]
        float* psum = ts + 3200;                 // [24][8]
        const int b = blk >> 7;
        const int i = blk & 127;

        const float* ab = att + ((size_t)b * N + i) * NT;
#pragma unroll
        for (int u = 0; u < 12; ++u) {
            const int idx = tid + 256 * u;
            const int j = idx / T, t = idx - j * T;
            ts[j * 25 + t] = ab[idx];
        }
        __syncthreads();
#pragma unroll
        for (int u = 0; u < 6; ++u) {
            const int e2 = tid + 256 * u;
            const int t = e2 >> 6, jp = e2 & 63, j = jp * 2;
            const unsigned pk = (unsigned)f2bf(ts[j * 25 + t])
                              | ((unsigned)f2bf(ts[(j + 1) * 25 + t]) << 16);
            attT32[((size_t)(b * T + t) * N + i) * 64 + jp] = pk;
        }
        if (tid < 192) {
            const int t = tid >> 3, p = tid & 7;
            float s = 0.f;
#pragma unroll
            for (int q = 0; q < 16; ++q) s += ts[(p * 16 + q) * 25 + t];
            psum[t * 8 + p] = s;
        }
        __syncthreads();
        if (tid < T) {
            float s = 0.f;
#pragma unroll
            for (int p = 0; p < 8; ++p) s += psum[tid * 8 + p];
            asum_g[(size_t)(b * T + tid) * N + i] = s;
        }
    } else if (blk < ATT_BLOCKS + XT_BLOCKS) {
        // ---- x transpose -> bf16 xT[bt][n][c']  (LDS [c'][97] u32, padded) ----
        const int tb = blk - ATT_BLOCKS;
        const int b  = tb >> 4;
        const int n0 = (tb & 15) * 8;
#pragma unroll
        for (int u = 0; u < 12; ++u) {
            const int vidx = tid + 256 * u;                 // < 3072
            const int cp = vidx / 48, w48 = vidx - cp * 48;
            const float4 v = *(const float4*)(x + (size_t)(b * CIN + cp) * NT
                                              + n0 * T + w48 * 4);
            smem_u32[cp * 97 + w48 * 2]     = (unsigned)f2bf(v.x) | ((unsigned)f2bf(v.y) << 16);
            smem_u32[cp * 97 + w48 * 2 + 1] = (unsigned)f2bf(v.z) | ((unsigned)f2bf(v.w) << 16);
        }
        __syncthreads();
#pragma unroll
        for (int v = 0; v < 24; ++v) {
            const int oidx = tid + 256 * v;                 // < 6144
            const int t = oidx >> 8, rem = oidx & 255;
            const int n = rem >> 5, cp = rem & 31;
            const int r = n * T + t;
            const unsigned w0 = smem_u32[(2 * cp) * 97 + (r >> 1)];
            const unsigned w1 = smem_u32[(2 * cp + 1) * 97 + (r >> 1)];
            const unsigned v0 = (r & 1) ? (w0 >> 16) : (w0 & 0xFFFFu);
            const unsigned v1 = (r & 1) ? (w1 >> 16) : (w1 & 0xFFFFu);
            xT32[((size_t)(b * T + t) * N + n0 + n) * 32 + cp] = v0 | (v1 << 16);
        }
    } else {
        // ---- fused weights, 16 parallel blocks: half = mv/mh, 8 cols each ----
        const int wf   = blk - (ATT_BLOCKS + XT_BLOCKS);    // 0..15
        const int half = wf >> 3;                           // 0: mv, 1: mh
        const int c0   = (wf & 7) * 8;
        float* sW1 = (float*)smem_u32;          // [64][65] padded
        float* sW2 = sW1 + 64 * 65;             // [64][65] padded
#pragma unroll
        for (int u = 0; u < 16; ++u) {
            const int i = tid + 256 * u;        // < 4096
            const int r = i >> 6, q = i & 63;
            sW1[r * 65 + q] = W1[i];
            sW2[r * 65 + q] = W2[half * 4096 + i];   // sW2[q][c] (q=row of half)
        }
        __syncthreads();

        const int c = c0 + (tid & 7);
        const int r = tid >> 3;                 // 0..31 -> rows r, r+32
        float a0 = 0.f, a1 = 0.f;
#pragma unroll
        for (int q = 0; q < 64; ++q) {
            const float w2 = sW2[q * 65 + c];
            a0 += sW1[r * 65 + q] * w2;
            a1 += sW1[(r + 32) * 65 + q] * w2;
        }
        unsigned short* dst = half ? WfhT : WfvT;
        dst[c * 64 + r]      = f2bf(a0);        // WfT[c][c'] k-major
        dst[c * 64 + r + 32] = f2bf(a1);

        if (tid < 8) {
            const int cb = c0 + tid;
            float s = 0.f;
#pragma unroll
            for (int q = 0; q < 64; ++q) s += b1[q] * sW2[q * 65 + cb];
            if (half) bh[cb] = s;
            else      bvb2[cb] = s + b2[cb];
        }
    }
}

// ---------------------------------------------------------------------------
// k_all (384 blocks = (bt, itile)), pure MFMA pipeline:
//  Phase 1: mh panel (128x64) = xT[bt] @ WfhT^T + bh  -> bf16 LDS mhT[64][140].
//           8 n-tiles x 2 MFMA; wave w owns c-tile w. At nt8==itile also
//           accumulates the mv tile with WfvT (A-frags reused).
//  Phase 2: einsum acc(16i x 16c) = attT_tile(16x128) @ mhT  (4 MFMA, B from LDS).
//  Epilogue: out[b][cc][i][t] = acc + asum_i * (accv + bvb2[cc])   (R7-verified).
//  A/B frags share the k-mapping (q4*8+e) -> any k-permutation cancels;
//  C/D: col=lane&15, row=(lane>>4)*4+reg (m89).
// ---------------------------------------------------------------------------
__global__ __launch_bounds__(256) void k_all(
    const unsigned short* __restrict__ xTb,
    const unsigned short* __restrict__ attTb,
    const unsigned short* __restrict__ WfvT,
    const unsigned short* __restrict__ WfhT,
    const float* __restrict__ bvb2,
    const float* __restrict__ bh,
    const float* __restrict__ asum_g,
    float* __restrict__ out)
{
    __shared__ __align__(8) unsigned short mhT[64][140];   // pad 140 (280B rows)

    const int blk   = blockIdx.x;
    const int itile = blk & 7;
    const int bt    = blk >> 3;
    const int b     = bt / T;
    const int t     = bt - b * T;

    const int tid  = threadIdx.x;
    const int w    = tid >> 6;
    const int lane = tid & 63;
    const int c16  = lane & 15;
    const int q4   = lane >> 4;
    const int cc   = w * 16 + c16;       // this lane's output channel

    const unsigned short* whr = WfhT + cc * 64;
    const short8 wh0 = *(const short8*)(whr + q4 * 8);
    const short8 wh1 = *(const short8*)(whr + 32 + q4 * 8);
    const unsigned short* wvr = WfvT + cc * 64;
    const short8 wv0 = *(const short8*)(wvr + q4 * 8);
    const short8 wv1 = *(const short8*)(wvr + 32 + q4 * 8);
    const float bhc = bh[cc];
    const float bvc = bvb2[cc];

    const unsigned short* xpanel = xTb + (size_t)bt * N * CIN;

    // Phase 1: mh panel -> LDS ; mv tile for own itile -> accv.
    f32x4 accv = {0.f, 0.f, 0.f, 0.f};
#pragma unroll
    for (int nt8 = 0; nt8 < 8; ++nt8) {
        const unsigned short* xr = xpanel + (nt8 * 16 + c16) * CIN;
        const short8 a0 = *(const short8*)(xr + q4 * 8);
        const short8 a1 = *(const short8*)(xr + 32 + q4 * 8);
        f32x4 d = {0.f, 0.f, 0.f, 0.f};
        d = __builtin_amdgcn_mfma_f32_16x16x32_bf16(a0, wh0, d, 0, 0, 0);
        d = __builtin_amdgcn_mfma_f32_16x16x32_bf16(a1, wh1, d, 0, 0, 0);
        // d[e] = mh[n = nt8*16 + q4*4 + e][cc]; store bf16 to mhT[cc][n]
        uint2 pk;
        pk.x = (unsigned)f2bf(d[0] + bhc) | ((unsigned)f2bf(d[1] + bhc) << 16);
        pk.y = (unsigned)f2bf(d[2] + bhc) | ((unsigned)f2bf(d[3] + bhc) << 16);
        *(uint2*)&mhT[cc][nt8 * 16 + q4 * 4] = pk;
        if (nt8 == itile) {   // block-uniform branch
            accv = __builtin_amdgcn_mfma_f32_16x16x32_bf16(a0, wv0, accv, 0, 0, 0);
            accv = __builtin_amdgcn_mfma_f32_16x16x32_bf16(a1, wv1, accv, 0, 0, 0);
        }
    }
    __syncthreads();

    // Phase 2: einsum (R6-anchored structure, B-frags from LDS).
    f32x4 acc = {0.f, 0.f, 0.f, 0.f};
    const unsigned short* arow = attTb + ((size_t)bt * N + itile * 16 + c16) * N;
#pragma unroll
    for (int ks = 0; ks < 4; ++ks) {
        const short8 a  = *(const short8*)(arow + ks * 32 + q4 * 8);
        const short8 bb = *(const short8*)(&mhT[cc][ks * 32 + q4 * 8]);
        acc = __builtin_amdgcn_mfma_f32_16x16x32_bf16(a, bb, acc, 0, 0, 0);
    }

    // Epilogue (R7-verified): out[b][cc][i][t] = acc + asum_i*(accv + bvb2)
    const int il0 = itile * 16 + q4 * 4;
    const f32x4 as4 = *(const f32x4*)(asum_g + (size_t)bt * N + il0);
    float* ob = out + (((size_t)b * COUT + cc) * N + il0) * T + t;
#pragma unroll
    for (int e = 0; e < 4; ++e) {
        ob[e * T] = acc[e] + as4[e] * (accv[e] + bvc);
    }
}

// ---------------------------------------------------------------------------
extern "C" void kernel_launch(void* const* d_in, const int* in_sizes, int n_in,
                              void* d_out, int out_size, void* d_ws, size_t ws_size,
                              hipStream_t stream)
{
    const float* x   = (const float*)d_in[0];
    const float* att = (const float*)d_in[1];
    const float* W1  = (const float*)d_in[2];
    const float* b1  = (const float*)d_in[3];
    const float* W2  = (const float*)d_in[4];
    const float* b2  = (const float*)d_in[5];
    float* out = (float*)d_out;

    // Workspace layout (bytes), all 16B-aligned:
    char* ws = (char*)d_ws;
    unsigned*       xT32   = (unsigned*)ws;                        //   786,432 B
    unsigned*       attT32 = (unsigned*)(ws + 786432);             // 1,572,864 B
    float*          asum_g = (float*)(ws + 2359296);               //    24,576 B
    unsigned short* WfvT   = (unsigned short*)(ws + 2383872);      //     8,192 B
    unsigned short* WfhT   = (unsigned short*)(ws + 2392064);      //     8,192 B
    float*          bvb2   = (float*)(ws + 2400256);               //       256 B
    float*          bh     = (float*)(ws + 2400512);               //       256 B

    k_prep<<<PREP_BLOCKS, 256, 0, stream>>>(x, att, W1, b1, W2, b2,
                                            xT32, attT32, asum_g,
                                            WfvT, WfhT, bvb2, bh);
    k_all<<<BT * 8, 256, 0, stream>>>((const unsigned short*)xT32,
                                      (const unsigned short*)attT32,
                                      WfvT, WfhT, bvb2, bh, asum_g, out);
}